// Round 1
// baseline (139.110 us; speedup 1.0000x reference)
//
#include <hip/hip_runtime.h>
#include <math.h>

// Dims fixed by reference setup_inputs
#define B_ 4
#define S_ 2048
#define D_ 1024
#define G_ 512
#define T_ 2047          // diff rows per batch
#define R_ 8188          // B_*T_ valid rows
#define RPAD 8192
#define MT 16            // diff rows per fused block (halved: grid 512 -> 2 blocks/CU)
#define ABST 1032        // AB LDS row stride (elems): 2064 B, 16-B aligned, 2-way bank alias

typedef __attribute__((ext_vector_type(8))) short short8;
typedef __attribute__((ext_vector_type(4))) short s16x4;
typedef __attribute__((ext_vector_type(4))) float f32x4;

// ws byte offsets
#define WSOFF_RG2  0u           // 512 f
#define WSOFF_MAGW 2048u        // 8192 f
#define WSOFF_BP1  34816u       // Bpack1 [128][512] short8 (1 MB)
#define WSOFF_BP2  1083392u     // Bpack2 [64][1024] short8 (1 MB)
#define WSOFF_NH   2131968u     // normh [8192][1024] bf16 (16 MB)
#define WSOFF_IH   18909184u    // inflh [8192][1024] bf16 (16 MB)

__device__ inline short to_bf16(float f) {
    union { float f; unsigned u; } v; v.f = f;
    unsigned r = v.u + 0x7fffu + ((v.u >> 16) & 1u);
    return (short)(r >> 16);
}
__device__ inline float fb(unsigned short h) {
    union { unsigned u; float f; } v;
    v.u = ((unsigned)h) << 16;
    return v.f;
}

// ---------------------------------------------------------------------------
// prep (merged prep1+prep2):
//  bid<128 : per-wave g = bid*4+wave: rg2[g] = 2/max(||guid[g]||,1e-8);
//            Bpack1[k/8][g][k&7] = bf16(guid[g][k])
//  bid>=128: gg = bid-128: Bpack2[gg][d][g&7] = bf16(guid[gg*8+j][d])
// ---------------------------------------------------------------------------
__global__ __launch_bounds__(256) void prep_kernel(const float* __restrict__ guid,
                                                   float* __restrict__ rg2,
                                                   short8* __restrict__ Bp1,
                                                   short8* __restrict__ Bp2) {
    int bid = blockIdx.x, tid = threadIdx.x;
    if (bid < 128) {
        int wave = tid >> 6, lane = tid & 63;
        int g = bid * 4 + wave;
        const float4* gp = (const float4*)(guid + (size_t)g * D_);
        float ss = 0.f;
#pragma unroll
        for (int i = 0; i < 4; ++i) {
            float4 v = gp[lane + 64 * i];
            ss += v.x * v.x + v.y * v.y + v.z * v.z + v.w * v.w;
        }
#pragma unroll
        for (int m = 32; m >= 1; m >>= 1) ss += __shfl_xor(ss, m, 64);
        if (lane == 0) rg2[g] = 2.0f / fmaxf(sqrtf(ss), 1e-8f);
#pragma unroll
        for (int h = 0; h < 2; ++h) {
            int kg = lane + 64 * h;
            const float* src = guid + (size_t)g * D_ + kg * 8;
            short8 v;
#pragma unroll
            for (int j = 0; j < 8; ++j) v[j] = to_bf16(src[j]);
            Bp1[(size_t)kg * G_ + g] = v;
        }
    } else {
        int gg = bid - 128;
#pragma unroll
        for (int dd = 0; dd < 4; ++dd) {
            int d = tid + 256 * dd;
            short8 v;
#pragma unroll
            for (int j = 0; j < 8; ++j) v[j] = to_bf16(guid[(size_t)(gg * 8 + j) * D_ + d]);
            Bp2[(size_t)gg * D_ + d] = v;
        }
    }
}

// ---------------------------------------------------------------------------
// fused: 16-row tile, 16 waves, grid 512 (2 blocks/CU co-resident).
// diff/norm -> gemm1 (full K staged in LDS) -> softmax -> gemm2 -> bf16 out.
// Register-slimmed to fit 8 waves/EU (unified V+A <= 64).
// ---------------------------------------------------------------------------
__global__ __launch_bounds__(1024, 8) void fused_kernel(const float* __restrict__ emb,
                                                        const short8* __restrict__ Bp1,
                                                        const short8* __restrict__ Bp2,
                                                        const float* __restrict__ rg2,
                                                        float* __restrict__ magw,
                                                        short* __restrict__ normh,
                                                        short* __restrict__ inflh) {
    __shared__ short AB[MT][ABST];      // normed rows (full K), then softmax weights
    __shared__ float rg2s[G_];
    __shared__ float pred[MT][16];
    __shared__ float redmx[MT], redrs[MT];

    const int tid = threadIdx.x;
    const int wave = tid >> 6, lane = tid & 63;
    const int l15 = lane & 15, quad = lane >> 4;
    const int r0 = blockIdx.x * MT;

    if (tid < G_) rg2s[tid] = rg2[tid];

    // ---- Phase 1: diff + normalize, 1 row/wave; full row -> LDS + normh ----
    {
        int rr = wave;
        int R = r0 + rr;
        if (R < R_) {
            int b = R / T_;
            int t = R - b * T_;
            const float4* p = (const float4*)(emb + ((size_t)b * S_ + t) * D_);
            float4 dv[4]; float ss = 0.f;
#pragma unroll
            for (int j = 0; j < 4; ++j) {
                float4 x0 = p[lane + 64 * j];
                float4 x1 = p[lane + 64 * j + 256];
                dv[j] = make_float4(x1.x - x0.x, x1.y - x0.y, x1.z - x0.z, x1.w - x0.w);
                ss += dv[j].x * dv[j].x + dv[j].y * dv[j].y + dv[j].z * dv[j].z + dv[j].w * dv[j].w;
            }
#pragma unroll
            for (int m = 32; m >= 1; m >>= 1) ss += __shfl_xor(ss, m, 64);
            float mag = sqrtf(ss);
            float rmag = (mag > 1e-6f) ? (1.0f / mag) : 0.0f;
            if (lane == 0) magw[R] = tanhf(2.0f * mag);
            short* nb = normh + (size_t)R * D_ + 4 * lane;
#pragma unroll
            for (int j = 0; j < 4; ++j) {
                s16x4 h;
                h[0] = to_bf16(dv[j].x * rmag); h[1] = to_bf16(dv[j].y * rmag);
                h[2] = to_bf16(dv[j].z * rmag); h[3] = to_bf16(dv[j].w * rmag);
                *(s16x4*)(nb + 256 * j) = h;
                *(s16x4*)&AB[rr][4 * lane + 256 * j] = h;
            }
        } else {
            s16x4 z = (s16x4)0;
#pragma unroll
            for (int j = 0; j < 4; ++j) *(s16x4*)&AB[rr][4 * lane + 256 * j] = z;
        }
    }
    __syncthreads();

    // ---- Phase 2: gemm1, full K=1024. wave owns g in [32w, 32w+32) ----
    f32x4 acc1[2];
    acc1[0] = (f32x4)0.f; acc1[1] = (f32x4)0.f;
    {
        const short8* Bb = Bp1 + (size_t)quad * G_ + wave * 32 + l15;
        short8 bc0 = Bb[0], bc1 = Bb[16], bn0, bn1;
        for (int ks = 0; ks < 32; ++ks) {
            if (ks < 31) {
                const short8* Bx = Bb + (size_t)(ks + 1) * 4 * G_;
                bn0 = Bx[0]; bn1 = Bx[16];
            }
            short8 a0 = *(const short8*)&AB[l15][ks * 32 + quad * 8];
            acc1[0] = __builtin_amdgcn_mfma_f32_16x16x32_bf16(a0, bc0, acc1[0], 0, 0, 0);
            acc1[1] = __builtin_amdgcn_mfma_f32_16x16x32_bf16(a0, bc1, acc1[1], 0, 0, 0);
            bc0 = bn0; bc1 = bn1;
        }
    }

    // ---- Phase 3: cross-wave softmax; weights -> AB (gemm2 A-frags) ----
    {
        float pmax[4];
#pragma unroll
        for (int r2 = 0; r2 < 4; ++r2) pmax[r2] = -1e30f;
#pragma unroll
        for (int nt = 0; nt < 2; ++nt) {
            float rgv = rg2s[wave * 32 + nt * 16 + l15];
#pragma unroll
            for (int r2 = 0; r2 < 4; ++r2) {
                float lg = acc1[nt][r2] * rgv;
                acc1[nt][r2] = lg;
                pmax[r2] = fmaxf(pmax[r2], lg);
            }
        }
#pragma unroll
        for (int m = 8; m >= 1; m >>= 1)
#pragma unroll
            for (int r2 = 0; r2 < 4; ++r2)
                pmax[r2] = fmaxf(pmax[r2], __shfl_xor(pmax[r2], m, 16));
        if (l15 == 0) {
#pragma unroll
            for (int r2 = 0; r2 < 4; ++r2)
                pred[quad * 4 + r2][wave] = pmax[r2];
        }
        __syncthreads();
        if (tid < MT) {
            float m = pred[tid][0];
#pragma unroll
            for (int w2 = 1; w2 < 16; ++w2) m = fmaxf(m, pred[tid][w2]);
            redmx[tid] = m;
        }
        __syncthreads();
        float psum[4];
#pragma unroll
        for (int r2 = 0; r2 < 4; ++r2) psum[r2] = 0.f;
#pragma unroll
        for (int nt = 0; nt < 2; ++nt)
#pragma unroll
            for (int r2 = 0; r2 < 4; ++r2) {
                float e = __expf(acc1[nt][r2] - redmx[quad * 4 + r2]);
                acc1[nt][r2] = e;
                psum[r2] += e;
            }
#pragma unroll
        for (int m = 8; m >= 1; m >>= 1)
#pragma unroll
            for (int r2 = 0; r2 < 4; ++r2)
                psum[r2] += __shfl_xor(psum[r2], m, 16);
        if (l15 == 0) {
#pragma unroll
            for (int r2 = 0; r2 < 4; ++r2)
                pred[quad * 4 + r2][wave] = psum[r2];
        }
        __syncthreads();
        if (tid < MT) {
            float s = 0.f;
#pragma unroll
            for (int w2 = 0; w2 < 16; ++w2) s += pred[tid][w2];
            redrs[tid] = 1.0f / s;
        }
        __syncthreads();
#pragma unroll
        for (int nt = 0; nt < 2; ++nt)
#pragma unroll
            for (int r2 = 0; r2 < 4; ++r2) {
                int row = quad * 4 + r2;
                AB[row][wave * 32 + nt * 16 + l15] =
                    to_bf16(acc1[nt][r2] * redrs[row]);
            }
    }
    __syncthreads();

    // ---- Phase 4: gemm2 in two 32-d halves (register-slim). wave owns d in [64w, 64w+64) ----
    f32x4 acc2[4];
#pragma unroll
    for (int nt = 0; nt < 4; ++nt) acc2[nt] = (f32x4)0.f;
#pragma unroll
    for (int half = 0; half < 2; ++half) {
        const short8* Bb = Bp2 + (size_t)quad * D_ + wave * 64 + half * 32 + l15;
        short8 bc0 = Bb[0], bc1 = Bb[16], bn0, bn1;
        for (int ks = 0; ks < 16; ++ks) {
            if (ks < 15) {
                const short8* Bx = Bb + (size_t)(ks + 1) * 4 * D_;
                bn0 = Bx[0]; bn1 = Bx[16];
            }
            short8 a0 = *(const short8*)&AB[l15][ks * 32 + quad * 8];
            acc2[half * 2 + 0] = __builtin_amdgcn_mfma_f32_16x16x32_bf16(a0, bc0, acc2[half * 2 + 0], 0, 0, 0);
            acc2[half * 2 + 1] = __builtin_amdgcn_mfma_f32_16x16x32_bf16(a0, bc1, acc2[half * 2 + 1], 0, 0, 0);
            bc0 = bn0; bc1 = bn1;
        }
    }

    // ---- Phase 5: influence bf16 out ----
#pragma unroll
    for (int half = 0; half < 2; ++half)
#pragma unroll
        for (int ntl = 0; ntl < 2; ++ntl) {
            int d = wave * 64 + half * 32 + ntl * 16 + l15;
#pragma unroll
            for (int r2 = 0; r2 < 4; ++r2) {
                int R = r0 + quad * 4 + r2;
                if (R < R_) inflh[(size_t)R * D_ + d] = to_bf16(acc2[half * 2 + ntl][r2]);
            }
        }
}

// ---------------------------------------------------------------------------
// combine: 8-tap ring over bf16 normh/inflh; block = 16 s x 512-d half.
// grid 1024 = B_ * 128 * 2
// ---------------------------------------------------------------------------
__global__ __launch_bounds__(256) void combine_kernel(const float* __restrict__ magw,
                                                      const unsigned short* __restrict__ normh,
                                                      const unsigned short* __restrict__ inflh,
                                                      float* __restrict__ out) {
    int blk = blockIdx.x;
    int b = blk >> 8;
    int rem = blk & 255;
    int s0 = (rem >> 1) * 16;
    int d = (rem & 1) * 512 + threadIdx.x * 2;
    size_t rbase = (size_t)b * T_;

    float2 ring[8]; float mring[8];
#pragma unroll
    for (int a2 = 0; a2 < 8; ++a2) { ring[a2] = make_float2(0.f, 0.f); mring[a2] = 0.f; }

#define LOADBL(t_, dst_)                                                        \
    {                                                                           \
        size_t off_ = (rbase + (t_)) * D_ + d;                                  \
        ushort2 n2_ = *(const ushort2*)(normh + off_);                          \
        ushort2 i2_ = *(const ushort2*)(inflh + off_);                          \
        dst_ = make_float2(0.6f * fb(n2_.x) + 0.4f * fb(i2_.x),                 \
                           0.6f * fb(n2_.y) + 0.4f * fb(i2_.y));                \
    }

#pragma unroll
    for (int a2 = 0; a2 < 7; ++a2) {
        int t = s0 - 8 + a2;
        if (t >= 0) {
            LOADBL(t, ring[a2]);
            mring[a2] = magw[rbase + t];
        }
    }
    if (s0 != 0) {
#pragma unroll
        for (int i = 0; i < 16; ++i) {
            int t = s0 + i - 1;
            LOADBL(t, ring[(i + 7) & 7]);
            mring[(i + 7) & 7] = magw[rbase + t];
            float2 acc = make_float2(0.f, 0.f); float wsum = 0.f;
#pragma unroll
            for (int a = 1; a <= 8; ++a) {
                int slot = (i - a) & 7;
                float lin = 0.1f + (0.9f / 7.0f) * (float)(8 - a);
                float wt = lin * mring[slot];
                acc.x += wt * ring[slot].x; acc.y += wt * ring[slot].y;
                wsum += wt;
            }
            float rws = 1.0f / fmaxf(wsum, 1e-8f);
            *(float2*)&out[((size_t)b * S_ + s0 + i) * D_ + d] =
                make_float2(acc.x * rws, acc.y * rws);
        }
    } else {
#pragma unroll
        for (int i = 0; i < 16; ++i) {
            if (i >= 1) {
                int t = i - 1;
                LOADBL(t, ring[(i + 7) & 7]);
                mring[(i + 7) & 7] = magw[rbase + t];
            }
            int w = (i < 8) ? i : 8;
            float rw = (w > 1) ? 0.9f / (float)(w - 1) : 0.0f;
            float2 acc = make_float2(0.f, 0.f); float wsum = 0.f;
            for (int a = 1; a <= w; ++a) {
                int slot = (i - a) & 7;
                float lin = 0.1f + rw * (float)(w - a);
                float wt = lin * mring[slot];
                acc.x += wt * ring[slot].x; acc.y += wt * ring[slot].y;
                wsum += wt;
            }
            float rws = 1.0f / fmaxf(wsum, 1e-8f);
            *(float2*)&out[((size_t)b * S_ + i) * D_ + d] =
                make_float2(acc.x * rws, acc.y * rws);
        }
    }
#undef LOADBL
}

// ---------------------------------------------------------------------------
extern "C" void kernel_launch(void* const* d_in, const int* in_sizes, int n_in,
                              void* d_out, int out_size, void* d_ws, size_t ws_size,
                              hipStream_t stream) {
    const float* emb  = (const float*)d_in[0];
    const float* guid = (const float*)d_in[1];
    float* out = (float*)d_out;
    char* ws = (char*)d_ws;

    float*  rg2   = (float*)(ws + WSOFF_RG2);
    float*  magw  = (float*)(ws + WSOFF_MAGW);
    short8* Bp1   = (short8*)(ws + WSOFF_BP1);
    short8* Bp2   = (short8*)(ws + WSOFF_BP2);
    short*  normh = (short*)(ws + WSOFF_NH);
    short*  inflh = (short*)(ws + WSOFF_IH);

    prep_kernel<<<192, 256, 0, stream>>>(guid, rg2, Bp1, Bp2);
    fused_kernel<<<RPAD / MT, 1024, 0, stream>>>(emb, Bp1, Bp2, rg2, magw, normh, inflh);
    combine_kernel<<<B_ * 128 * 2, 256, 0, stream>>>(magw, (const unsigned short*)normh,
                                                     (const unsigned short*)inflh, out);
}

// Round 2
// 127.026 us; speedup vs baseline: 1.0951x; 1.0951x over previous
//
#include <hip/hip_runtime.h>
#include <math.h>

// Dims fixed by reference setup_inputs
#define B_ 4
#define S_ 2048
#define D_ 1024
#define G_ 512
#define T_ 2047          // diff rows per batch
#define R_ 8188          // B_*T_ valid rows
#define RPAD 8192
#define MT 32            // diff rows per fused block (grid 256 = 1 block/CU: minimal B L2 traffic)
#define ABST 520         // AB LDS row stride (elems): 1040 B, 16-B aligned, 2-way bank alias

typedef __attribute__((ext_vector_type(8))) short short8;
typedef __attribute__((ext_vector_type(4))) short s16x4;
typedef __attribute__((ext_vector_type(4))) float f32x4;
typedef __attribute__((ext_vector_type(4))) unsigned short u16x4;

// ws byte offsets
#define WSOFF_RG2  0u           // 512 f
#define WSOFF_MAGW 2048u        // 8192 f
#define WSOFF_RMAG 34816u       // 8192 f
#define WSOFF_BP1  67584u       // Bpack1 [128][512] short8 (1 MB)
#define WSOFF_BP2  1116160u     // Bpack2 [64][1024] short8 (1 MB)
#define WSOFF_NH   2164736u     // normh (RAW diffs) [8192][1024] bf16 (16 MB)
#define WSOFF_IH   18941952u    // inflh [8192][1024] bf16 (16 MB)

__device__ inline short to_bf16(float f) {
    union { float f; unsigned u; } v; v.f = f;
    unsigned r = v.u + 0x7fffu + ((v.u >> 16) & 1u);
    return (short)(r >> 16);
}
__device__ inline float fb(unsigned short h) {
    union { unsigned u; float f; } v;
    v.u = ((unsigned)h) << 16;
    return v.f;
}

// ---------------------------------------------------------------------------
// prep (merged):
//  bid<128 : per-wave g = bid*4+wave: rg2[g] = 2/max(||guid[g]||,1e-8);
//            Bpack1[k/8][g][k&7] = bf16(guid[g][k])
//  bid>=128: gg = bid-128: Bpack2[gg][d][j] = bf16(guid[gg*8+j][d])
// ---------------------------------------------------------------------------
__global__ __launch_bounds__(256) void prep_kernel(const float* __restrict__ guid,
                                                   float* __restrict__ rg2,
                                                   short8* __restrict__ Bp1,
                                                   short8* __restrict__ Bp2) {
    int bid = blockIdx.x, tid = threadIdx.x;
    if (bid < 128) {
        int wave = tid >> 6, lane = tid & 63;
        int g = bid * 4 + wave;
        const float4* gp = (const float4*)(guid + (size_t)g * D_);
        float ss = 0.f;
#pragma unroll
        for (int i = 0; i < 4; ++i) {
            float4 v = gp[lane + 64 * i];
            ss += v.x * v.x + v.y * v.y + v.z * v.z + v.w * v.w;
        }
#pragma unroll
        for (int m = 32; m >= 1; m >>= 1) ss += __shfl_xor(ss, m, 64);
        if (lane == 0) rg2[g] = 2.0f / fmaxf(sqrtf(ss), 1e-8f);
#pragma unroll
        for (int h = 0; h < 2; ++h) {
            int kg = lane + 64 * h;
            const float* src = guid + (size_t)g * D_ + kg * 8;
            short8 v;
#pragma unroll
            for (int j = 0; j < 8; ++j) v[j] = to_bf16(src[j]);
            Bp1[(size_t)kg * G_ + g] = v;
        }
    } else {
        int gg = bid - 128;
#pragma unroll
        for (int dd = 0; dd < 4; ++dd) {
            int d = tid + 256 * dd;
            short8 v;
#pragma unroll
            for (int j = 0; j < 8; ++j) v[j] = to_bf16(guid[(size_t)(gg * 8 + j) * D_ + d]);
            Bp2[(size_t)gg * D_ + d] = v;
        }
    }
}

// ---------------------------------------------------------------------------
// fused: 32-row tile, 16 waves, grid 256 (1 block/CU).
// Deferred normalization: gemm1 runs on RAW bf16 diffs (dots are linear);
// rmag folded into softmax prescale. k>=512 emb loads are issued before a
// NON-vmcnt-draining barrier so they overlap gemm1 pass 0.
// ---------------------------------------------------------------------------
__global__ __launch_bounds__(1024, 4) void fused_kernel(const float* __restrict__ emb,
                                                        const short8* __restrict__ Bp1,
                                                        const short8* __restrict__ Bp2,
                                                        const float* __restrict__ rg2,
                                                        float* __restrict__ magw,
                                                        float* __restrict__ rmagA,
                                                        short* __restrict__ normh,
                                                        short* __restrict__ inflh) {
    __shared__ short AB[MT][ABST];      // raw diff halves, then softmax weights
    __shared__ float rg2s[G_];
    __shared__ float pred[MT][16];
    __shared__ float redmx[MT], redrs[MT];
    __shared__ float rmagS[MT];

    const int tid = threadIdx.x;
    const int wave = tid >> 6, lane = tid & 63;
    const int l15 = lane & 15, quad = lane >> 4;
    const int r0 = blockIdx.x * MT;

    if (tid < G_) rg2s[tid] = rg2[tid];

    // ---- Phase 1a: rows 2w,2w+1: k<512 diff -> raw bf16 LDS + normh;
    //      k>=512 raw emb loads ISSUED into hold regs (used after gemm pass0) ----
    float4 hx0[2][2], hx1[2][2];
    float ssp[2];
    int Rrow[2];
#pragma unroll
    for (int i = 0; i < 2; ++i) {
        int rr = wave * 2 + i;
        int R = r0 + rr;
        Rrow[i] = R;
        if (R < R_) {
            int b = R / T_;
            int t = R - b * T_;
            const float4* p = (const float4*)(emb + ((size_t)b * S_ + t) * D_);
            float ss = 0.f;
            short* nb = normh + (size_t)R * D_ + 4 * lane;
#pragma unroll
            for (int j = 0; j < 2; ++j) {
                float4 x0 = p[lane + 64 * j];
                float4 x1 = p[lane + 64 * j + 256];
                float4 dv = make_float4(x1.x - x0.x, x1.y - x0.y, x1.z - x0.z, x1.w - x0.w);
                ss += dv.x * dv.x + dv.y * dv.y + dv.z * dv.z + dv.w * dv.w;
                s16x4 h;
                h[0] = to_bf16(dv.x); h[1] = to_bf16(dv.y);
                h[2] = to_bf16(dv.z); h[3] = to_bf16(dv.w);
                *(s16x4*)(nb + 256 * j) = h;
                *(s16x4*)&AB[rr][4 * lane + 256 * j] = h;
            }
            ssp[i] = ss;
#pragma unroll
            for (int j = 0; j < 2; ++j) {
                hx0[i][j] = p[lane + 64 * (j + 2)];
                hx1[i][j] = p[lane + 64 * (j + 2) + 256];
            }
        } else {
            s16x4 z = (s16x4)0;
            *(s16x4*)&AB[rr][4 * lane] = z;
            *(s16x4*)&AB[rr][4 * lane + 256] = z;
            ssp[i] = 0.f;
#pragma unroll
            for (int j = 0; j < 2; ++j) {
                hx0[i][j] = make_float4(0.f, 0.f, 0.f, 0.f);
                hx1[i][j] = make_float4(0.f, 0.f, 0.f, 0.f);
            }
        }
    }
    // non-draining barrier: LDS writes visible, k>=512 global loads stay in flight
    __builtin_amdgcn_sched_barrier(0);
    asm volatile("s_waitcnt lgkmcnt(0)" ::: "memory");
    __builtin_amdgcn_s_barrier();

    // ---- Phase 2a: gemm1 pass 0 (k < 512). wave owns g in [32w, 32w+32) ----
    f32x4 acc1[2][2];
#pragma unroll
    for (int mt = 0; mt < 2; ++mt)
#pragma unroll
        for (int nt = 0; nt < 2; ++nt) acc1[mt][nt] = (f32x4)0.f;
    {
        const short8* Bb = Bp1 + (size_t)quad * G_ + wave * 32 + l15;
        short8 bc0 = Bb[0], bc1 = Bb[16], bn0, bn1;
        for (int ks = 0; ks < 16; ++ks) {
            if (ks < 15) {
                const short8* Bx = Bb + (size_t)(ks + 1) * 4 * G_;
                bn0 = Bx[0]; bn1 = Bx[16];
            }
            short8 a0 = *(const short8*)&AB[l15][ks * 32 + quad * 8];
            short8 a1 = *(const short8*)&AB[16 + l15][ks * 32 + quad * 8];
            acc1[0][0] = __builtin_amdgcn_mfma_f32_16x16x32_bf16(a0, bc0, acc1[0][0], 0, 0, 0);
            acc1[0][1] = __builtin_amdgcn_mfma_f32_16x16x32_bf16(a0, bc1, acc1[0][1], 0, 0, 0);
            acc1[1][0] = __builtin_amdgcn_mfma_f32_16x16x32_bf16(a1, bc0, acc1[1][0], 0, 0, 0);
            acc1[1][1] = __builtin_amdgcn_mfma_f32_16x16x32_bf16(a1, bc1, acc1[1][1], 0, 0, 0);
            bc0 = bn0; bc1 = bn1;
        }
    }

    // ---- Phase 1b: finish k>=512 halves, full-row norm, rmag ----
    s16x4 holdh[2][2];
#pragma unroll
    for (int i = 0; i < 2; ++i) {
        int R = Rrow[i];
        int rr = wave * 2 + i;
        float ss = ssp[i];
        if (R < R_) {
            short* nb = normh + (size_t)R * D_ + 4 * lane;
#pragma unroll
            for (int j = 0; j < 2; ++j) {
                float4 dv = make_float4(hx1[i][j].x - hx0[i][j].x, hx1[i][j].y - hx0[i][j].y,
                                        hx1[i][j].z - hx0[i][j].z, hx1[i][j].w - hx0[i][j].w);
                ss += dv.x * dv.x + dv.y * dv.y + dv.z * dv.z + dv.w * dv.w;
                s16x4 h;
                h[0] = to_bf16(dv.x); h[1] = to_bf16(dv.y);
                h[2] = to_bf16(dv.z); h[3] = to_bf16(dv.w);
                *(s16x4*)(nb + 256 * (j + 2)) = h;
                holdh[i][j] = h;
            }
        } else {
            holdh[i][0] = (s16x4)0; holdh[i][1] = (s16x4)0;
        }
#pragma unroll
        for (int m = 32; m >= 1; m >>= 1) ss += __shfl_xor(ss, m, 64);
        float mag = sqrtf(ss);
        float rmag = (mag > 1e-6f) ? (1.0f / mag) : 0.0f;
        if (lane == 0) {
            rmagS[rr] = rmag;
            if (R < R_) { magw[R] = tanhf(2.0f * mag); rmagA[R] = rmag; }
        }
    }
    __syncthreads();     // all pass-0 LDS reads done
#pragma unroll
    for (int i = 0; i < 2; ++i) {
        int rr = wave * 2 + i;
        *(s16x4*)&AB[rr][4 * lane] = holdh[i][0];
        *(s16x4*)&AB[rr][4 * lane + 256] = holdh[i][1];
    }
    __syncthreads();

    // ---- Phase 2b: gemm1 pass 1 (k >= 512) ----
    {
        const short8* Bb = Bp1 + (size_t)(64 + quad) * G_ + wave * 32 + l15;
        short8 bc0 = Bb[0], bc1 = Bb[16], bn0, bn1;
        for (int ks = 0; ks < 16; ++ks) {
            if (ks < 15) {
                const short8* Bx = Bb + (size_t)(ks + 1) * 4 * G_;
                bn0 = Bx[0]; bn1 = Bx[16];
            }
            short8 a0 = *(const short8*)&AB[l15][ks * 32 + quad * 8];
            short8 a1 = *(const short8*)&AB[16 + l15][ks * 32 + quad * 8];
            acc1[0][0] = __builtin_amdgcn_mfma_f32_16x16x32_bf16(a0, bc0, acc1[0][0], 0, 0, 0);
            acc1[0][1] = __builtin_amdgcn_mfma_f32_16x16x32_bf16(a0, bc1, acc1[0][1], 0, 0, 0);
            acc1[1][0] = __builtin_amdgcn_mfma_f32_16x16x32_bf16(a1, bc0, acc1[1][0], 0, 0, 0);
            acc1[1][1] = __builtin_amdgcn_mfma_f32_16x16x32_bf16(a1, bc1, acc1[1][1], 0, 0, 0);
            bc0 = bn0; bc1 = bn1;
        }
    }

    // ---- Phase 3: cross-wave softmax (rmag folded in); weights -> AB ----
    {
        float rmv[2][4];
#pragma unroll
        for (int mt = 0; mt < 2; ++mt)
#pragma unroll
            for (int r2 = 0; r2 < 4; ++r2) rmv[mt][r2] = rmagS[mt * 16 + quad * 4 + r2];
        float pmax[2][4];
#pragma unroll
        for (int mt = 0; mt < 2; ++mt)
#pragma unroll
            for (int r2 = 0; r2 < 4; ++r2) pmax[mt][r2] = -1e30f;
#pragma unroll
        for (int mt = 0; mt < 2; ++mt)
#pragma unroll
            for (int nt = 0; nt < 2; ++nt) {
                float rgv = rg2s[wave * 32 + nt * 16 + l15];
#pragma unroll
                for (int r2 = 0; r2 < 4; ++r2) {
                    float lg = acc1[mt][nt][r2] * rgv * rmv[mt][r2];
                    acc1[mt][nt][r2] = lg;
                    pmax[mt][r2] = fmaxf(pmax[mt][r2], lg);
                }
            }
#pragma unroll
        for (int m = 8; m >= 1; m >>= 1)
#pragma unroll
            for (int mt = 0; mt < 2; ++mt)
#pragma unroll
                for (int r2 = 0; r2 < 4; ++r2)
                    pmax[mt][r2] = fmaxf(pmax[mt][r2], __shfl_xor(pmax[mt][r2], m, 16));
        if (l15 == 0) {
#pragma unroll
            for (int mt = 0; mt < 2; ++mt)
#pragma unroll
                for (int r2 = 0; r2 < 4; ++r2)
                    pred[mt * 16 + quad * 4 + r2][wave] = pmax[mt][r2];
        }
        __syncthreads();
        if (tid < MT) {
            float m = pred[tid][0];
#pragma unroll
            for (int w2 = 1; w2 < 16; ++w2) m = fmaxf(m, pred[tid][w2]);
            redmx[tid] = m;
        }
        __syncthreads();
        float psum[2][4];
#pragma unroll
        for (int mt = 0; mt < 2; ++mt)
#pragma unroll
            for (int r2 = 0; r2 < 4; ++r2) psum[mt][r2] = 0.f;
#pragma unroll
        for (int mt = 0; mt < 2; ++mt)
#pragma unroll
            for (int nt = 0; nt < 2; ++nt)
#pragma unroll
                for (int r2 = 0; r2 < 4; ++r2) {
                    float e = __expf(acc1[mt][nt][r2] - redmx[mt * 16 + quad * 4 + r2]);
                    acc1[mt][nt][r2] = e;
                    psum[mt][r2] += e;
                }
#pragma unroll
        for (int m = 8; m >= 1; m >>= 1)
#pragma unroll
            for (int mt = 0; mt < 2; ++mt)
#pragma unroll
                for (int r2 = 0; r2 < 4; ++r2)
                    psum[mt][r2] += __shfl_xor(psum[mt][r2], m, 16);
        if (l15 == 0) {
#pragma unroll
            for (int mt = 0; mt < 2; ++mt)
#pragma unroll
                for (int r2 = 0; r2 < 4; ++r2)
                    pred[mt * 16 + quad * 4 + r2][wave] = psum[mt][r2];
        }
        __syncthreads();
        if (tid < MT) {
            float s = 0.f;
#pragma unroll
            for (int w2 = 0; w2 < 16; ++w2) s += pred[tid][w2];
            redrs[tid] = 1.0f / s;
        }
        __syncthreads();
#pragma unroll
        for (int mt = 0; mt < 2; ++mt)
#pragma unroll
            for (int nt = 0; nt < 2; ++nt)
#pragma unroll
                for (int r2 = 0; r2 < 4; ++r2) {
                    int row = mt * 16 + quad * 4 + r2;
                    AB[row][wave * 32 + nt * 16 + l15] =
                        to_bf16(acc1[mt][nt][r2] * redrs[row]);
                }
    }
    __syncthreads();

    // ---- Phase 4: gemm2. wave owns d in [64w, 64w+64) ----
    f32x4 acc2[2][4];
#pragma unroll
    for (int mt = 0; mt < 2; ++mt)
#pragma unroll
        for (int nt = 0; nt < 4; ++nt) acc2[mt][nt] = (f32x4)0.f;
    {
        const short8* Bb = Bp2 + (size_t)quad * D_ + wave * 64 + l15;
        short8 bc[4], bn[4];
#pragma unroll
        for (int nt = 0; nt < 4; ++nt) bc[nt] = Bb[nt * 16];
        for (int ks = 0; ks < 16; ++ks) {
            if (ks < 15) {
                const short8* Bx = Bb + (size_t)(ks + 1) * 4 * D_;
#pragma unroll
                for (int nt = 0; nt < 4; ++nt) bn[nt] = Bx[nt * 16];
            }
            short8 a0 = *(const short8*)&AB[l15][ks * 32 + quad * 8];
            short8 a1 = *(const short8*)&AB[16 + l15][ks * 32 + quad * 8];
#pragma unroll
            for (int nt = 0; nt < 4; ++nt) {
                acc2[0][nt] = __builtin_amdgcn_mfma_f32_16x16x32_bf16(a0, bc[nt], acc2[0][nt], 0, 0, 0);
                acc2[1][nt] = __builtin_amdgcn_mfma_f32_16x16x32_bf16(a1, bc[nt], acc2[1][nt], 0, 0, 0);
            }
#pragma unroll
            for (int nt = 0; nt < 4; ++nt) bc[nt] = bn[nt];
        }
    }

    // ---- Phase 5: influence bf16 out ----
#pragma unroll
    for (int mt = 0; mt < 2; ++mt)
#pragma unroll
        for (int nt = 0; nt < 4; ++nt) {
            int d = wave * 64 + nt * 16 + l15;
#pragma unroll
            for (int r2 = 0; r2 < 4; ++r2) {
                int R = r0 + mt * 16 + quad * 4 + r2;
                if (R < R_) inflh[(size_t)R * D_ + d] = to_bf16(acc2[mt][nt][r2]);
            }
        }
}

// ---------------------------------------------------------------------------
// combine: 8-tap ring over RAW bf16 normh (scaled by rmag at load) + inflh.
// block = 16 s x 1024 d, 256 threads, 4 d-elems/thread (8B loads, 16B stores).
// grid 512 = B_ * 128. Ring prefetched one step ahead.
// ---------------------------------------------------------------------------
__global__ __launch_bounds__(256) void combine_kernel(const float* __restrict__ magw,
                                                      const float* __restrict__ rmagA,
                                                      const unsigned short* __restrict__ normh,
                                                      const unsigned short* __restrict__ inflh,
                                                      float* __restrict__ out) {
    int blk = blockIdx.x;
    int b = blk >> 7;
    int s0 = (blk & 127) * 16;     // multiple of 16 -> (s0+x)&7 == x&7 (static slots)
    int d0 = threadIdx.x * 4;
    size_t rbase = (size_t)b * T_;

    f32x4 ring[8]; float mring[8];
#pragma unroll
    for (int j = 0; j < 8; ++j) { ring[j] = (f32x4)0.f; mring[j] = 0.f; }

#define BLEND(n4_, i4_, ns_, dst_)                                       \
    {                                                                    \
        dst_[0] = ns_ * fb(n4_[0]) + 0.4f * fb(i4_[0]);                  \
        dst_[1] = ns_ * fb(n4_[1]) + 0.4f * fb(i4_[1]);                  \
        dst_[2] = ns_ * fb(n4_[2]) + 0.4f * fb(i4_[2]);                  \
        dst_[3] = ns_ * fb(n4_[3]) + 0.4f * fb(i4_[3]);                  \
    }

    if (s0 != 0) {
#pragma unroll
        for (int j = 0; j < 8; ++j) {
            int t = s0 - 8 + j;
            size_t off = (rbase + t) * D_ + d0;
            u16x4 n4 = *(const u16x4*)(normh + off);
            u16x4 i4 = *(const u16x4*)(inflh + off);
            float ns = 0.6f * rmagA[rbase + t];
            BLEND(n4, i4, ns, ring[j]);
            mring[j] = magw[rbase + t];
        }
#pragma unroll
        for (int i = 0; i < 16; ++i) {
            u16x4 pn = (u16x4)0, pi = (u16x4)0; float pm = 0.f, pr = 0.f;
            if (i < 15) {
                int t = s0 + i;
                size_t off = (rbase + t) * D_ + d0;
                pn = *(const u16x4*)(normh + off);
                pi = *(const u16x4*)(inflh + off);
                pm = magw[rbase + t];
                pr = rmagA[rbase + t];
            }
            f32x4 acc = (f32x4)0.f; float wsum = 0.f;
#pragma unroll
            for (int a = 1; a <= 8; ++a) {
                int slot = (i - a) & 7;
                const float lin = 0.1f + (0.9f / 7.0f) * (float)(8 - a);
                float wt = lin * mring[slot];
                acc[0] += wt * ring[slot][0]; acc[1] += wt * ring[slot][1];
                acc[2] += wt * ring[slot][2]; acc[3] += wt * ring[slot][3];
                wsum += wt;
            }
            float rws = 1.0f / fmaxf(wsum, 1e-8f);
            f32x4 o; o[0] = acc[0] * rws; o[1] = acc[1] * rws; o[2] = acc[2] * rws; o[3] = acc[3] * rws;
            *(f32x4*)&out[((size_t)b * S_ + s0 + i) * D_ + d0] = o;
            if (i < 15) {
                float ns = 0.6f * pr;
                BLEND(pn, pi, ns, ring[i & 7]);
                mring[i & 7] = pm;
            }
        }
    } else {
#pragma unroll
        for (int i = 0; i < 16; ++i) {
            u16x4 pn = (u16x4)0, pi = (u16x4)0; float pm = 0.f, pr = 0.f;
            if (i < 15) {
                int t = i;
                size_t off = (rbase + t) * D_ + d0;
                pn = *(const u16x4*)(normh + off);
                pi = *(const u16x4*)(inflh + off);
                pm = magw[rbase + t];
                pr = rmagA[rbase + t];
            }
            const int w = (i < 8) ? i : 8;
            f32x4 acc = (f32x4)0.f; float wsum = 0.f;
            if (w > 0) {
                const float rw = (w > 1) ? 0.9f / (float)(w - 1) : 0.0f;
#pragma unroll
                for (int a = 1; a <= 8; ++a) {
                    if (a <= w) {
                        int slot = (i - a) & 7;
                        float lin = 0.1f + rw * (float)(w - a);
                        float wt = lin * mring[slot];
                        acc[0] += wt * ring[slot][0]; acc[1] += wt * ring[slot][1];
                        acc[2] += wt * ring[slot][2]; acc[3] += wt * ring[slot][3];
                        wsum += wt;
                    }
                }
            }
            float rws = 1.0f / fmaxf(wsum, 1e-8f);
            f32x4 o; o[0] = acc[0] * rws; o[1] = acc[1] * rws; o[2] = acc[2] * rws; o[3] = acc[3] * rws;
            *(f32x4*)&out[((size_t)b * S_ + i) * D_ + d0] = o;
            if (i < 15) {
                float ns = 0.6f * pr;
                BLEND(pn, pi, ns, ring[i & 7]);
                mring[i & 7] = pm;
            }
        }
    }
#undef BLEND
}

// ---------------------------------------------------------------------------
extern "C" void kernel_launch(void* const* d_in, const int* in_sizes, int n_in,
                              void* d_out, int out_size, void* d_ws, size_t ws_size,
                              hipStream_t stream) {
    const float* emb  = (const float*)d_in[0];
    const float* guid = (const float*)d_in[1];
    float* out = (float*)d_out;
    char* ws = (char*)d_ws;

    float*  rg2   = (float*)(ws + WSOFF_RG2);
    float*  magw  = (float*)(ws + WSOFF_MAGW);
    float*  rmagA = (float*)(ws + WSOFF_RMAG);
    short8* Bp1   = (short8*)(ws + WSOFF_BP1);
    short8* Bp2   = (short8*)(ws + WSOFF_BP2);
    short*  normh = (short*)(ws + WSOFF_NH);
    short*  inflh = (short*)(ws + WSOFF_IH);

    prep_kernel<<<192, 256, 0, stream>>>(guid, rg2, Bp1, Bp2);
    fused_kernel<<<RPAD / MT, 1024, 0, stream>>>(emb, Bp1, Bp2, rg2, magw, rmagA, normh, inflh);
    combine_kernel<<<B_ * 128, 256, 0, stream>>>(magw, rmagA, (const unsigned short*)normh,
                                                 (const unsigned short*)inflh, out);
}